// Round 6
// baseline (412.840 us; speedup 1.0000x reference)
//
#include <hip/hip_runtime.h>
#include <hip/hip_bf16.h>

#define BB 2
#define NN 2048
#define DD 128
#define BN (BB*NN)
#define CAP 128
#define TD 16
#define INV_SQRT_D 0.08838834764831845f

typedef __attribute__((ext_vector_type(8))) short short8;
typedef __attribute__((ext_vector_type(4))) float f32x4;

__device__ __forceinline__ float bf2f(short u) {
    union { unsigned int i; float f; } t;
    t.i = ((unsigned int)(unsigned short)u) << 16;
    return t.f;
}
__device__ __forceinline__ float2 bf2x2(unsigned int u) {
    union { unsigned int i; float f; } a, b;
    a.i = u << 16; b.i = u & 0xffff0000u;
    float2 r; r.x = a.f; r.y = b.f; return r;
}

// ---------------------------------------------------------------------------
// LDS-tiled CSR build of e_t[b,dst,src] = edge[b,src,dst]*A[b,src,dst].
// cols[] stores GLOBAL src row (b*NN + src).
// ---------------------------------------------------------------------------
__global__ __launch_bounds__(256) void build_csr(
    const float* __restrict__ A,
    const float* __restrict__ edge,
    int* __restrict__ deg, int* __restrict__ cols, float* __restrict__ evals)
{
    __shared__ int   cnt[TD];
    __shared__ int   csh[TD][CAP];
    __shared__ float esh[TD][CAP];

    int bid  = blockIdx.x;
    int b    = bid / (NN / TD);
    int dst0 = (bid % (NN / TD)) * TD;
    int tid  = threadIdx.x;

    if (tid < TD) cnt[tid] = 0;
    __syncthreads();

    int srcOff = tid >> 2;
    int dOff   = (tid & 3) * 4;
    const size_t base = (size_t)b * NN * NN + dst0 + dOff;

#pragma unroll 2
    for (int s0 = 0; s0 < NN; s0 += 64) {
        int src = s0 + srcOff;
        float4 a4 = *(const float4*)&A[base + (size_t)src * NN];
        float4 e4 = *(const float4*)&edge[base + (size_t)src * NN];
        int gsrc = b * NN + src;
        float av[4] = {a4.x, a4.y, a4.z, a4.w};
        float ev[4] = {e4.x, e4.y, e4.z, e4.w};
#pragma unroll
        for (int u = 0; u < 4; u++) {
            if (av[u] != 0.f) {
                int d = dOff + u;
                int slot = atomicAdd(&cnt[d], 1);
                if (slot < CAP) { csh[d][slot] = gsrc; esh[d][slot] = ev[u] * av[u]; }
            }
        }
    }
    __syncthreads();

    if (tid < TD) deg[b * NN + dst0 + tid] = min(cnt[tid], CAP);
    for (int idx = tid; idx < TD * CAP; idx += 256) {
        int d = idx / CAP, i = idx % CAP;
        if (i < min(cnt[d], CAP)) {
            size_t row = (size_t)(b * NN + dst0 + d);
            cols [row * CAP + i] = csh[d][i];
            evals[row * CAP + i] = esh[d][i];
        }
    }
}

// ---------------------------------------------------------------------------
// Weight prep: Wt[n][k] = W*[k][n] as bf16, cols concat [q | k | v | skip].
// ---------------------------------------------------------------------------
__global__ __launch_bounds__(128) void prep_weights(
    const float* __restrict__ Wq, const float* __restrict__ Wk,
    const float* __restrict__ Wv, const float* __restrict__ Ws,
    __hip_bfloat16* __restrict__ Wt, int HD)
{
    int n = blockIdx.x;
    int t = threadIdx.x;
    const float* src; int ld; int col;
    if      (n < HD)     { src = Wq; col = n;          ld = HD; }
    else if (n < 2*HD)   { src = Wk; col = n - HD;     ld = HD; }
    else if (n < 3*HD)   { src = Wv; col = n - 2*HD;   ld = HD; }
    else                 { src = Ws; col = n - 3*HD;   ld = DD; }
    Wt[(size_t)n * DD + t] = __float2bfloat16(src[(size_t)t * ld + col]);
}

// ---------------------------------------------------------------------------
// Layer-0 projection (FIN=1, rank-1). q/skip fp32; k/v bf16.
// ---------------------------------------------------------------------------
__global__ __launch_bounds__(128) void proj_l0(
    const float* __restrict__ x,
    const float* __restrict__ Wq, const float* __restrict__ Wk,
    const float* __restrict__ Wv, const float* __restrict__ Ws,
    float* __restrict__ q, __hip_bfloat16* __restrict__ kb,
    __hip_bfloat16* __restrict__ vb, float* __restrict__ skip)
{
    __shared__ float xs[16];
    int row0 = blockIdx.x * 16;
    int col  = blockIdx.y * 128 + threadIdx.x;
    if (threadIdx.x < 16) xs[threadIdx.x] = x[row0 + threadIdx.x];
    __syncthreads();

    if (col < DD) {
        float wf = Wq[col];
#pragma unroll
        for (int r = 0; r < 16; r++) q[(size_t)(row0 + r) * DD + col] = xs[r] * wf;
    } else if (col < 2*DD) {
        float wf = Wk[col - DD];
#pragma unroll
        for (int r = 0; r < 16; r++) kb[(size_t)(row0 + r) * DD + col - DD] = __float2bfloat16(xs[r] * wf);
    } else if (col < 3*DD) {
        float wf = Wv[col - 2*DD];
#pragma unroll
        for (int r = 0; r < 16; r++) vb[(size_t)(row0 + r) * DD + col - 2*DD] = __float2bfloat16(xs[r] * wf);
    } else {
        float wf = Ws[col - 3*DD];
#pragma unroll
        for (int r = 0; r < 16; r++) skip[(size_t)(row0 + r) * DD + col - 3*DD] = xs[r] * wf;
    }
}

// ---------------------------------------------------------------------------
// MFMA bf16 projection. q/skip fp32 out; k/v bf16 out.
// Wave = 16x64 tile, K=128 in 4 steps. C/D: col=lane&15, row=quad*4+reg.
// ---------------------------------------------------------------------------
template<int HD>
__global__ __launch_bounds__(256) void proj_mfma(
    const __hip_bfloat16* __restrict__ xb,
    const __hip_bfloat16* __restrict__ Wt,
    float* __restrict__ q, __hip_bfloat16* __restrict__ kb,
    __hip_bfloat16* __restrict__ vb, float* __restrict__ skip)
{
    int wid  = threadIdx.x >> 6, lane = threadIdx.x & 63;
    int row0 = blockIdx.x * 64 + wid * 16;
    int n0   = blockIdx.y * 64;
    int m    = lane & 15, quad = lane >> 4;

    f32x4 acc[4] = {f32x4{0,0,0,0}, f32x4{0,0,0,0}, f32x4{0,0,0,0}, f32x4{0,0,0,0}};
    const short8* ap = (const short8*)&xb[(size_t)(row0 + m) * DD + quad * 8];
#pragma unroll
    for (int ks = 0; ks < 4; ks++) {
        short8 a = ap[ks * 4];
#pragma unroll
        for (int t = 0; t < 4; t++) {
            const short8* bp = (const short8*)&Wt[(size_t)(n0 + t * 16 + m) * DD + ks * 32 + quad * 8];
            acc[t] = __builtin_amdgcn_mfma_f32_16x16x32_bf16(a, *bp, acc[t], 0, 0, 0);
        }
    }

    if (n0 < HD) {                      // q (fp32)
        int lc0 = n0;
#pragma unroll
        for (int t = 0; t < 4; t++)
#pragma unroll
            for (int r = 0; r < 4; r++)
                q[(size_t)(row0 + quad * 4 + r) * HD + lc0 + t * 16 + m] = acc[t][r];
    } else if (n0 < 2 * HD) {           // k (bf16)
        int lc0 = n0 - HD;
#pragma unroll
        for (int t = 0; t < 4; t++)
#pragma unroll
            for (int r = 0; r < 4; r++)
                kb[(size_t)(row0 + quad * 4 + r) * HD + lc0 + t * 16 + m] = __float2bfloat16(acc[t][r]);
    } else if (n0 < 3 * HD) {           // v (bf16)
        int lc0 = n0 - 2 * HD;
#pragma unroll
        for (int t = 0; t < 4; t++)
#pragma unroll
            for (int r = 0; r < 4; r++)
                vb[(size_t)(row0 + quad * 4 + r) * HD + lc0 + t * 16 + m] = __float2bfloat16(acc[t][r]);
    } else {                            // skip (fp32)
        int lc0 = n0 - 3 * HD;
#pragma unroll
        for (int t = 0; t < 4; t++)
#pragma unroll
            for (int r = 0; r < 4; r++)
                skip[(size_t)(row0 + quad * 4 + r) * DD + lc0 + t * 16 + m] = acc[t][r];
    }
}

// ---------------------------------------------------------------------------
// Sparse attention: one wave per dst, 4/block, NO LDS.
// Edges held in registers (2/lane), fetched via shfl. 8 edges/group,
// 8 lanes/edge, 16 ch/lane. k/v gathered in bf16 (L2-resident).
// ---------------------------------------------------------------------------
template<int H, bool MEANH, bool LNRELU, bool OUTBF>
__global__ __launch_bounds__(256) void attn_kernel(
    const float* __restrict__ q, const __hip_bfloat16* __restrict__ kb,
    const __hip_bfloat16* __restrict__ vb, const float* __restrict__ skip,
    const int* __restrict__ deg, const int* __restrict__ cols,
    const float* __restrict__ evals, const float* __restrict__ We,
    void* __restrict__ outv)
{
    const int HD = H * DD;
    int wid  = threadIdx.x >> 6;
    int lane = threadIdx.x & 63;
    int row  = blockIdx.x * 4 + wid;
    int sub  = lane >> 3;          // edge slot in 8-edge group
    int s    = lane & 7;           // 16-ch slice
    int c0   = lane * 2;

    int dg = min(deg[row], CAP);
    int   jreg0 = cols [(size_t)row * CAP + lane];
    float ereg0 = evals[(size_t)row * CAP + lane];
    int   jreg1 = cols [(size_t)row * CAP + 64 + lane];
    float ereg1 = evals[(size_t)row * CAP + 64 + lane];

    // q fragment: 16 ch per lane; qe[h] = q . We[h] (8-lane butterfly)
    float qh[H][16];
    float qeI[H];
#pragma unroll
    for (int h = 0; h < H; h++) {
        const float* qp = &q[(size_t)row * HD + h * DD + s * 16];
        const float* wp = &We[h * DD + s * 16];
        float pe = 0.f;
#pragma unroll
        for (int t = 0; t < 16; t++) { qh[h][t] = qp[t]; pe += qp[t] * wp[t]; }
        pe += __shfl_xor(pe, 1); pe += __shfl_xor(pe, 2); pe += __shfl_xor(pe, 4);
        qeI[h] = pe * INV_SQRT_D;
    }

    float l_acc[H], ew_acc[H], acc[H][2];
#pragma unroll
    for (int h = 0; h < H; h++) { l_acc[h] = 0.f; ew_acc[h] = 0.f; acc[h][0] = 0.f; acc[h][1] = 0.f; }

    for (int m0 = 0; m0 < dg; m0 += 8) {
        // own edge (per-lane): index via register shuffles
        int   e  = m0 + sub;
        bool  ok = e < dg;
        int   ec = ok ? e : m0;
        int   jA = __shfl(jreg0, ec & 63), jB = __shfl(jreg1, ec & 63);
        int   j  = (ec < 64) ? jA : jB;
        float fA = __shfl(ereg0, ec & 63), fB = __shfl(ereg1, ec & 63);
        float ee = (ec < 64) ? fA : fB;

        // per-es (uniform) rows for v loads
        unsigned int vvr[H][8];
#pragma unroll
        for (int es = 0; es < 8; es++) {
            int e2 = m0 + es;
            int mc = (e2 < dg) ? e2 : m0;                      // uniform
            int jv = (mc < 64) ? __shfl(jreg0, mc) : __shfl(jreg1, mc & 63);
#pragma unroll
            for (int h = 0; h < H; h++)
                vvr[h][es] = *(const unsigned int*)&vb[(size_t)jv * HD + h * DD + c0];
        }

        float a8[H];
#pragma unroll
        for (int h = 0; h < H; h++) {
            const short8* kp = (const short8*)&kb[(size_t)j * HD + h * DD + s * 16];
            short8 kA = kp[0], kB = kp[1];
            float p = 0.f;
#pragma unroll
            for (int t = 0; t < 8; t++) p += qh[h][t] * bf2f(kA[t]);
#pragma unroll
            for (int t = 0; t < 8; t++) p += qh[h][8 + t] * bf2f(kB[t]);
            p += __shfl_xor(p, 1); p += __shfl_xor(p, 2); p += __shfl_xor(p, 4);
            float sc = ok ? (p * INV_SQRT_D + qeI[h] * ee) : -1e30f;
            a8[h] = __expf(fminf(sc, 60.f));
            l_acc[h]  += a8[h];
            ew_acc[h] += a8[h] * ee;
        }

#pragma unroll
        for (int h = 0; h < H; h++)
#pragma unroll
            for (int es = 0; es < 8; es++) {
                float  al = __shfl(a8[h], es * 8);
                float2 vf = bf2x2(vvr[h][es]);
                acc[h][0] += al * vf.x;
                acc[h][1] += al * vf.y;
            }
    }

    // reduce l/ew across the 8 subgroups (replicated within subgroup)
    float rh[H][2];
#pragma unroll
    for (int h = 0; h < H; h++) {
        float l  = l_acc[h], ew = ew_acc[h];
        l += __shfl_xor(l, 8);  ew += __shfl_xor(ew, 8);
        l += __shfl_xor(l, 16); ew += __shfl_xor(ew, 16);
        l += __shfl_xor(l, 32); ew += __shfl_xor(ew, 32);
        float invZ = (l > 0.f) ? 1.f / l : 0.f;
        rh[h][0] = (acc[h][0] + ew * We[h * DD + c0])     * invZ;
        rh[h][1] = (acc[h][1] + ew * We[h * DD + c0 + 1]) * invZ;
    }
    float r0, r1;
    if constexpr (MEANH) {
        r0 = 0.5f * (rh[0][0] + rh[H - 1][0]);
        r1 = 0.5f * (rh[0][1] + rh[H - 1][1]);
    } else {
        r0 = rh[0][0]; r1 = rh[0][1];
    }
    float2 sk = *(const float2*)&skip[(size_t)row * DD + c0];
    r0 += sk.x; r1 += sk.y;

    if constexpr (LNRELU) {
        float sum = r0 + r1, sq = r0 * r0 + r1 * r1;
#pragma unroll
        for (int off = 32; off; off >>= 1) { sum += __shfl_xor(sum, off); sq += __shfl_xor(sq, off); }
        float mu  = sum * (1.f / DD);
        float var = sq * (1.f / DD) - mu * mu;
        float rs  = rsqrtf(var + 1e-5f);
        r0 = fmaxf((r0 - mu) * rs, 0.f);
        r1 = fmaxf((r1 - mu) * rs, 0.f);
    }

    if constexpr (OUTBF) {
        __hip_bfloat16* ob = (__hip_bfloat16*)outv;
        __hip_bfloat162 o;
        o.x = __float2bfloat16(r0);
        o.y = __float2bfloat16(r1);
        *(__hip_bfloat162*)&ob[(size_t)row * DD + c0] = o;
    } else {
        float2 res; res.x = r0; res.y = r1;
        *(float2*)&((float*)outv)[(size_t)row * DD + c0] = res;
    }
}

// ---------------------------------------------------------------------------
extern "C" void kernel_launch(void* const* d_in, const int* in_sizes, int n_in,
                              void* d_out, int out_size, void* d_ws, size_t ws_size,
                              hipStream_t stream)
{
    const float* node = (const float*)d_in[0];
    const float* edge = (const float*)d_in[1];
    const float* A    = (const float*)d_in[2];
    const float* Wq[3] = {(const float*)d_in[3],  (const float*)d_in[8],  (const float*)d_in[13]};
    const float* Wk[3] = {(const float*)d_in[4],  (const float*)d_in[9],  (const float*)d_in[14]};
    const float* Wv[3] = {(const float*)d_in[5],  (const float*)d_in[10], (const float*)d_in[15]};
    const float* We[3] = {(const float*)d_in[6],  (const float*)d_in[11], (const float*)d_in[16]};
    const float* Ws[3] = {(const float*)d_in[7],  (const float*)d_in[12], (const float*)d_in[17]};

    // workspace carve
    char* p = (char*)d_ws;
    float*          qbuf = (float*)p;          p += (size_t)BN * 256 * 4;
    __hip_bfloat16* kbuf = (__hip_bfloat16*)p; p += (size_t)BN * 256 * 2;
    __hip_bfloat16* vbuf = (__hip_bfloat16*)p; p += (size_t)BN * 256 * 2;
    float*          sbuf = (float*)p;          p += (size_t)BN * DD * 4;
    __hip_bfloat16* xb   = (__hip_bfloat16*)p; p += (size_t)BN * DD * 2;
    __hip_bfloat16* Wt1  = (__hip_bfloat16*)p; p += (size_t)512 * DD * 2;
    __hip_bfloat16* Wt2  = (__hip_bfloat16*)p; p += (size_t)896 * DD * 2;
    int*            degb = (int*)p;            p += (size_t)BN * 4;
    int*            colb = (int*)p;            p += (size_t)BN * CAP * 4;
    float*          evb  = (float*)p;          p += (size_t)BN * CAP * 4;

    build_csr<<<BB * (NN / TD), 256, 0, stream>>>(A, edge, degb, colb, evb);
    prep_weights<<<512, 128, 0, stream>>>(Wq[1], Wk[1], Wv[1], Ws[1], Wt1, DD);
    prep_weights<<<896, 128, 0, stream>>>(Wq[2], Wk[2], Wv[2], Ws[2], Wt2, 2 * DD);

    const int appL[7] = {0, 1, 2, 1, 2, 1, 2};

    for (int a = 0; a < 7; a++) {
        int l = appL[a];
        if (l == 0) {
            proj_l0<<<dim3(BN / 16, 4), 128, 0, stream>>>(node, Wq[0], Wk[0], Wv[0], Ws[0],
                                                          qbuf, kbuf, vbuf, sbuf);
        } else if (l == 1) {
            proj_mfma<DD><<<dim3(BN / 64, 8), 256, 0, stream>>>(xb, Wt1, qbuf, kbuf, vbuf, sbuf);
        } else {
            proj_mfma<2 * DD><<<dim3(BN / 64, 14), 256, 0, stream>>>(xb, Wt2, qbuf, kbuf, vbuf, sbuf);
        }
        if (l == 2) {
            if (a == 6)
                attn_kernel<2, true, false, false><<<BN / 4, 256, 0, stream>>>(
                    qbuf, kbuf, vbuf, sbuf, degb, colb, evb, We[l], d_out);
            else
                attn_kernel<2, true, false, true><<<BN / 4, 256, 0, stream>>>(
                    qbuf, kbuf, vbuf, sbuf, degb, colb, evb, We[l], xb);
        } else {
            attn_kernel<1, false, true, true><<<BN / 4, 256, 0, stream>>>(
                qbuf, kbuf, vbuf, sbuf, degb, colb, evb, We[l], xb);
        }
    }
}